// Round 16
// baseline (137.391 us; speedup 1.0000x reference)
//
#include <hip/hip_runtime.h>
#include <hip/hip_bf16.h>

typedef unsigned short u16;
typedef float  f32x4  __attribute__((ext_vector_type(4)));
typedef __bf16 bf16x8 __attribute__((ext_vector_type(8)));
typedef unsigned short u16x8 __attribute__((ext_vector_type(8)));
typedef unsigned short u16x4 __attribute__((ext_vector_type(4)));

__device__ __forceinline__ u16 f2bfu(float f) {
    __hip_bfloat16 h = __float2bfloat16(f);
    return __builtin_bit_cast(unsigned short, h);
}

constexpr int kHW = 196;   // 14*14
constexpr int kKC = 17;    // ceil(196/12) k-chunks (12 k rows per tile)
constexpr int kLC = 25;    // ceil(196/8)  l-chunks (8 l rows per tile)
constexpr int kChunks = kKC * kLC;  // 425 per batch

// ---------------- prep: interleave weights [k>>3][n][k8] bf16 ----------------
__global__ __launch_bounds__(256)
void k_prep(const float* __restrict__ pw, u16* __restrict__ pwi,
            const float* __restrict__ w1, u16* __restrict__ w1li, u16* __restrict__ w1ki,
            const float* __restrict__ w2, u16* __restrict__ w2i,
            const float* __restrict__ w3, u16* __restrict__ w3i) {
    int id = blockIdx.x;
    int n = threadIdx.x;
    if (id < 512) {
        int k = id;
        pwi[((k >> 3) << 11) + (n << 3) + (k & 7)] = f2bfu(pw[n * 512 + k]);
    } else {
        int k = (id - 512) & 255;
        int idx = ((k >> 3) << 11) + (n << 3) + (k & 7);
        if (id < 768)       w1li[idx] = f2bfu(w1[k * 256 + n]);
        else if (id < 1024) w1ki[idx] = f2bfu(w1[(k + 256) * 256 + n]);
        else if (id < 1280) w2i[idx]  = f2bfu(w2[k * 256 + n]);
        else                w3i[idx]  = f2bfu(w3[k * 256 + n]);
    }
}

// ---------------- MFMA prologue: xf then al/ak. grid (14, 8), 256 thr ----------------
__global__ __launch_bounds__(256, 2)
void k_xa3(const float* __restrict__ im, const u16* __restrict__ pwi,
           const float* __restrict__ pb, const u16* __restrict__ w1li,
           const u16* __restrict__ w1ki, float* __restrict__ al,
           float* __restrict__ ak) {
    __shared__ u16 imT[16 * 512];   // [p][i] bf16, swizzled rows (1KB), 16KB
    __shared__ u16 xfs[16 * 256];   // [p][c] bf16, swizzled rows (512B), 8KB
    const int tid = threadIdx.x;
    const int b = blockIdx.y;
    const int p0 = blockIdx.x * 14;

    {
        int t4 = tid & 3;
        int ibase = tid >> 2;
#pragma unroll
        for (int it = 0; it < 8; ++it) {
            int i = it * 64 + ibase;
            const float* src = im + (b * 512 + i) * kHW;
#pragma unroll
            for (int j = 0; j < 4; ++j) {
                int prow = t4 * 4 + j;
                int p = p0 + prow; if (p > 195) p = 195;
                int byte = (prow << 10) + (i << 1);
                byte ^= (prow & 7) << 4;
                *(u16*)((char*)imT + byte) = f2bfu(src[p]);
            }
        }
    }
    __syncthreads();

    const int lane = tid & 63;
    const int wn = tid >> 6;
    const int l15 = lane & 15;
    const int kg = lane >> 4;
    const int wbase = (wn * 64 + l15) << 3;

    f32x4 acc[4];
#pragma unroll
    for (int fn = 0; fn < 4; ++fn) acc[fn] = f32x4{0.f, 0.f, 0.f, 0.f};
    for (int kk = 0; kk < 16; ++kk) {
        int kb = kk * 32 + kg * 8;
        int byte = (l15 << 10) + (kb << 1);
        byte ^= (l15 & 7) << 4;
        bf16x8 hb = __builtin_bit_cast(bf16x8, *(const u16x8*)((const char*)imT + byte));
        const u16* wp = pwi + ((((kk << 2) + kg) << 11) + wbase);
#pragma unroll
        for (int fn = 0; fn < 4; ++fn) {
            bf16x8 aw = __builtin_bit_cast(bf16x8, *(const u16x8*)(wp + (fn << 7)));
            acc[fn] = __builtin_amdgcn_mfma_f32_16x16x32_bf16(aw, hb, acc[fn], 0, 0, 0);
        }
    }
#pragma unroll
    for (int fn = 0; fn < 4; ++fn) {
        f32x4 pbv = *(const f32x4*)(pb + wn * 64 + fn * 16 + kg * 4);
        u16x4 pv;
#pragma unroll
        for (int r = 0; r < 4; ++r) pv[r] = f2bfu(acc[fn][r] + pbv[r]);
        int byte = (l15 << 9) + ((wn * 64 + fn * 16 + kg * 4) << 1);
        byte ^= (l15 & 7) << 4;
        *(u16x4*)((char*)xfs + byte) = pv;
    }
    __syncthreads();

    const int p = p0 + l15;
    const bool valid = (l15 < 14) && (p < kHW);
#pragma unroll
    for (int sel = 0; sel < 2; ++sel) {
        const u16* wsrc = sel ? w1ki : w1li;
        f32x4 a2[4];
#pragma unroll
        for (int fn = 0; fn < 4; ++fn) a2[fn] = f32x4{0.f, 0.f, 0.f, 0.f};
        for (int kk = 0; kk < 8; ++kk) {
            int kb = kk * 32 + kg * 8;
            int byte = (l15 << 9) + (kb << 1);
            byte ^= (l15 & 7) << 4;
            bf16x8 hb = __builtin_bit_cast(bf16x8, *(const u16x8*)((const char*)xfs + byte));
            const u16* wp = wsrc + ((((kk << 2) + kg) << 11) + wbase);
#pragma unroll
            for (int fn = 0; fn < 4; ++fn) {
                bf16x8 aw = __builtin_bit_cast(bf16x8, *(const u16x8*)(wp + (fn << 7)));
                a2[fn] = __builtin_amdgcn_mfma_f32_16x16x32_bf16(aw, hb, a2[fn], 0, 0, 0);
            }
        }
        if (valid) {
            float* dst = (sel ? ak : al) + ((b * kHW + p) << 8) + wn * 64 + kg * 4;
#pragma unroll
            for (int fn = 0; fn < 4; ++fn) *(f32x4*)(dst + fn * 16) = a2[fn];
        }
    }
}

// ---------------- main v13: 96-pair tiles (12k x 8l), 3 blocks/CU ------------------
// grid (25 lc, 17 kc, 8 b) = 3400 blocks, block 256 (4 waves; wave = ch quarter).
// acc[4][6] = 96 AGPR + aw/hb/addr ~ 160 live < (256,3) cap ~170. LDS 48KB x 3 = 144.
__global__ __launch_bounds__(256, 3)
void k_main13(const float* __restrict__ ak, const float* __restrict__ al,
              const float* __restrict__ b1, const u16* __restrict__ w2i,
              const float* __restrict__ b2, const u16* __restrict__ w3i,
              const float* __restrict__ b3, float* __restrict__ part) {
    __shared__ u16 smem[96 * 256];  // 48 KB: h1, then h2 in-place
    const int tid = threadIdx.x;
    const int lc = blockIdx.x, kc = blockIdx.y, b = blockIdx.z;
    const int k0 = kc * 12, l0 = lc * 8;

    // ---- build h1 = relu(ak[k]+al[l]+b1) -> bf16 LDS [pair][ch] ----
    {
        const int cc = tid & 31;
        f32x4 c0v = *(const f32x4*)(b1 + (cc << 3));
        f32x4 c1v = *(const f32x4*)(b1 + (cc << 3) + 4);
#pragma unroll
        for (int it = 0; it < 12; ++it) {
            int row = (it * 256 + tid) >> 5;  // 0..95 = (ki-k0)*8 + (li-l0)
            int ki = k0 + (row >> 3); if (ki > 195) ki = 195;
            int li = l0 + (row & 7);  if (li > 195) li = 195;
            const float* akp = ak + ((b * kHW + ki) << 8) + (cc << 3);
            const float* alp = al + ((b * kHW + li) << 8) + (cc << 3);
            f32x4 k0v = *(const f32x4*)akp;
            f32x4 k1v = *(const f32x4*)(akp + 4);
            f32x4 l0v = *(const f32x4*)alp;
            f32x4 l1v = *(const f32x4*)(alp + 4);
            u16x8 v;
#pragma unroll
            for (int j = 0; j < 4; ++j) {
                v[j]     = f2bfu(fmaxf(k0v[j] + l0v[j] + c0v[j], 0.f));
                v[4 + j] = f2bfu(fmaxf(k1v[j] + l1v[j] + c1v[j], 0.f));
            }
            int byte = (row << 9) + (cc << 4);
            byte ^= (row & 7) << 4;
            *(u16x8*)((char*)smem + byte) = v;
        }
    }
    __syncthreads();

    const int lane = tid & 63;
    const int wn = tid >> 6;   // wave = ch quarter 0..3
    const int l15 = lane & 15;
    const int kg = lane >> 4;  // 0..3
    const int wbase = (wn * 64 + l15) << 3;

    f32x4 acc[4][6];  // [fn ch-frag][fm pair-frag], reused for both GEMMs

    // ---- GEMM1: h2^T = w2 x h1^T (aw preloaded, hb streamed) ----
#pragma unroll
    for (int fn = 0; fn < 4; ++fn)
#pragma unroll
        for (int fm = 0; fm < 6; ++fm) acc[fn][fm] = f32x4{0.f, 0.f, 0.f, 0.f};
    for (int kk = 0; kk < 8; ++kk) {
        int kb = kk * 32 + kg * 8;
        const u16* wp = w2i + ((((kk << 2) + kg) << 11) + wbase);
        bf16x8 aw[4];
#pragma unroll
        for (int fn = 0; fn < 4; ++fn)
            aw[fn] = __builtin_bit_cast(bf16x8, *(const u16x8*)(wp + (fn << 7)));
#pragma unroll
        for (int fm = 0; fm < 6; ++fm) {
            int row = fm * 16 + l15;
            int byte = (row << 9) + (kb << 1);
            byte ^= (row & 7) << 4;
            bf16x8 hb = __builtin_bit_cast(bf16x8, *(const u16x8*)((const char*)smem + byte));
#pragma unroll
            for (int fn = 0; fn < 4; ++fn)
                acc[fn][fm] = __builtin_amdgcn_mfma_f32_16x16x32_bf16(aw[fn], hb, acc[fn][fm], 0, 0, 0);
        }
    }
    __syncthreads();

    // ---- epilogue: h2 = relu(D1 + b2) -> bf16 LDS, packed 8B writes ----
#pragma unroll
    for (int fn = 0; fn < 4; ++fn) {
        f32x4 b2v = *(const f32x4*)(b2 + wn * 64 + fn * 16 + kg * 4);
#pragma unroll
        for (int fm = 0; fm < 6; ++fm) {
            int prow = fm * 16 + l15;
            u16x4 pv;
#pragma unroll
            for (int r = 0; r < 4; ++r)
                pv[r] = f2bfu(fmaxf(acc[fn][fm][r] + b2v[r], 0.f));
            int byte = (prow << 9) + ((wn * 64 + fn * 16 + kg * 4) << 1);
            byte ^= (prow & 7) << 4;
            *(u16x4*)((char*)smem + byte) = pv;
        }
    }
    __syncthreads();

    // ---- GEMM2: h3^T = w3 x h2^T ----
#pragma unroll
    for (int fn = 0; fn < 4; ++fn)
#pragma unroll
        for (int fm = 0; fm < 6; ++fm) acc[fn][fm] = f32x4{0.f, 0.f, 0.f, 0.f};
    for (int kk = 0; kk < 8; ++kk) {
        int kb = kk * 32 + kg * 8;
        const u16* wp = w3i + ((((kk << 2) + kg) << 11) + wbase);
        bf16x8 aw[4];
#pragma unroll
        for (int fn = 0; fn < 4; ++fn)
            aw[fn] = __builtin_bit_cast(bf16x8, *(const u16x8*)(wp + (fn << 7)));
#pragma unroll
        for (int fm = 0; fm < 6; ++fm) {
            int row = fm * 16 + l15;
            int byte = (row << 9) + (kb << 1);
            byte ^= (row & 7) << 4;
            bf16x8 hb = __builtin_bit_cast(bf16x8, *(const u16x8*)((const char*)smem + byte));
#pragma unroll
            for (int fn = 0; fn < 4; ++fn)
                acc[fn][fm] = __builtin_amdgcn_mfma_f32_16x16x32_bf16(aw[fn], hb, acc[fn][fm], 0, 0, 0);
        }
    }

    // ---- masked col-sum + 16-lane reduce + store to part ----
    float s[4][4] = {};
#pragma unroll
    for (int fm = 0; fm < 6; ++fm) {
        int pr = fm * 16 + l15;
        int ki = k0 + (pr >> 3);
        int li = l0 + (pr & 7);
        float vm = (ki < kHW && li < kHW) ? 1.f : 0.f;
#pragma unroll
        for (int fn = 0; fn < 4; ++fn) {
            f32x4 b3v = *(const f32x4*)(b3 + wn * 64 + fn * 16 + kg * 4);
#pragma unroll
            for (int r = 0; r < 4; ++r)
                s[fn][r] += vm * fmaxf(acc[fn][fm][r] + b3v[r], 0.f);
        }
    }
#pragma unroll
    for (int fn = 0; fn < 4; ++fn)
#pragma unroll
        for (int r = 0; r < 4; ++r) {
            s[fn][r] += __shfl_xor(s[fn][r], 1);
            s[fn][r] += __shfl_xor(s[fn][r], 2);
            s[fn][r] += __shfl_xor(s[fn][r], 4);
            s[fn][r] += __shfl_xor(s[fn][r], 8);
        }
    if (l15 == 0) {
        int chunkid = (b * kKC + kc) * kLC + lc;
        float* pp = part + chunkid * 256 + wn * 64 + kg * 4;
#pragma unroll
        for (int fn = 0; fn < 4; ++fn)
            *(f32x4*)(pp + fn * 16) = f32x4{s[fn][0], s[fn][1], s[fn][2], s[fn][3]};
    }
}

// ---------------- final reduce: 64 blocks (b x 8 ch-octants) ----------------
__global__ __launch_bounds__(256)
void k_reduce(const float* __restrict__ part, float* __restrict__ out) {
    __shared__ float red[256];
    int b = blockIdx.x >> 3, s = blockIdx.x & 7;
    int c32 = threadIdx.x & 31, stripe = threadIdx.x >> 5;
    int c = s * 32 + c32;
    const float* p = part + b * kChunks * 256 + c;
    float sum = 0.f;
    for (int j = stripe; j < kChunks; j += 8) sum += p[j * 256];
    red[threadIdx.x] = sum;
    __syncthreads();
    if (threadIdx.x < 32) {
        float t = 0.f;
#pragma unroll
        for (int st = 0; st < 8; ++st) t += red[st * 32 + c32];
        out[b * 256 + c] = t;
    }
}

extern "C" void kernel_launch(void* const* d_in, const int* in_sizes, int n_in,
                              void* d_out, int out_size, void* d_ws, size_t ws_size,
                              hipStream_t stream) {
    const float* im = (const float*)d_in[0];
    const float* pw = (const float*)d_in[3];
    const float* pb = (const float*)d_in[4];
    const float* w1 = (const float*)d_in[5];
    const float* b1 = (const float*)d_in[6];
    const float* w2 = (const float*)d_in[7];
    const float* b2 = (const float*)d_in[8];
    const float* w3 = (const float*)d_in[9];
    const float* b3 = (const float*)d_in[10];
    float* out = (float*)d_out;

    float* al  = (float*)d_ws;            // 8*196*256
    float* ak  = al + 8 * 196 * 256;
    u16* pwi  = (u16*)(ak + 8 * 196 * 256);  // [64 k8-blk][256 n][8 k]
    u16* w1li = pwi + 512 * 256;             // [32 k8-blk][256 n][8 k]
    u16* w1ki = w1li + 256 * 256;
    u16* w2i  = w1ki + 256 * 256;
    u16* w3i  = w2i + 256 * 256;
    float* part = (float*)(w3i + 256 * 256); // [8*425][256] = 3.48 MB

    hipLaunchKernelGGL(k_prep, dim3(1536), dim3(256), 0, stream,
                       pw, pwi, w1, w1li, w1ki, w2, w2i, w3, w3i);
    hipLaunchKernelGGL(k_xa3, dim3(14, 8), dim3(256), 0, stream,
                       im, pwi, pb, w1li, w1ki, al, ak);
    hipLaunchKernelGGL(k_main13, dim3(kLC, kKC, 8), dim3(256), 0, stream,
                       ak, al, b1, w2i, b2, w3i, b3, part);
    hipLaunchKernelGGL(k_reduce, dim3(64), dim3(256), 0, stream, part, out);
}

// Round 17
// 129.632 us; speedup vs baseline: 1.0599x; 1.0599x over previous
//
#include <hip/hip_runtime.h>
#include <hip/hip_bf16.h>

typedef unsigned short u16;
typedef float  f32x4  __attribute__((ext_vector_type(4)));
typedef __bf16 bf16x8 __attribute__((ext_vector_type(8)));
typedef unsigned short u16x8 __attribute__((ext_vector_type(8)));
typedef unsigned short u16x4 __attribute__((ext_vector_type(4)));

__device__ __forceinline__ u16 f2bfu(float f) {
    __hip_bfloat16 h = __float2bfloat16(f);
    return __builtin_bit_cast(unsigned short, h);
}

constexpr int kHW = 196;   // 14*14
constexpr int kKC = 13;    // ceil(196/16) k-chunks (16 k rows per tile)
constexpr int kLC = 25;    // ceil(196/8)  l-chunks (8 l rows per tile)
constexpr int kChunks = kKC * kLC;  // 325 per batch

// ---------------- prep: interleave weights [k>>3][n][k8] bf16 ----------------
// pw path: block = n row, threads = k -> coalesced reads (was a 64-line gather).
__global__ __launch_bounds__(256)
void k_prep(const float* __restrict__ pw, u16* __restrict__ pwi,
            const float* __restrict__ w1, u16* __restrict__ w1li, u16* __restrict__ w1ki,
            const float* __restrict__ w2, u16* __restrict__ w2i,
            const float* __restrict__ w3, u16* __restrict__ w3i) {
    int id = blockIdx.x;
    int t = threadIdx.x;
    if (id < 256) {
        int n = id;
#pragma unroll
        for (int h = 0; h < 2; ++h) {
            int k = h * 256 + t;
            pwi[((k >> 3) << 11) + (n << 3) + (k & 7)] = f2bfu(pw[n * 512 + k]);
        }
    } else {
        int k = (id - 256) & 255;
        int idx = ((k >> 3) << 11) + (t << 3) + (k & 7);
        if (id < 512)       w1li[idx] = f2bfu(w1[k * 256 + t]);
        else if (id < 768)  w1ki[idx] = f2bfu(w1[(k + 256) * 256 + t]);
        else if (id < 1024) w2i[idx]  = f2bfu(w2[k * 256 + t]);
        else                w3i[idx]  = f2bfu(w3[k * 256 + t]);
    }
}

// ---------------- MFMA prologue: xf then al/ak. grid (28, 8), 256 thr --------------
// 7 p's per block (28*7=196 exact): doubled block count for CU coverage.
// imT/xfs hold 8 p-rows; lanes 8-15 compute discarded duplicates.
__global__ __launch_bounds__(256, 2)
void k_xa4(const float* __restrict__ im, const u16* __restrict__ pwi,
           const float* __restrict__ pb, const u16* __restrict__ w1li,
           const u16* __restrict__ w1ki, float* __restrict__ al,
           float* __restrict__ ak) {
    __shared__ u16 imT[8 * 512];   // [p][i] bf16, swizzled rows (1KB), 8KB
    __shared__ u16 xfs[8 * 256];   // [p][c] bf16, swizzled rows (512B), 4KB
    const int tid = threadIdx.x;
    const int b = blockIdx.y;
    const int p0 = blockIdx.x * 7;

    // ---- stage imT[prow][i] = bf16(im[b][i][p0+prow]), prow 0..7 ----
    {
        int t2 = tid & 1;
        int ibase = tid >> 1;   // 0..127
#pragma unroll
        for (int it = 0; it < 4; ++it) {
            int i = it * 128 + ibase;
            const float* src = im + (b * 512 + i) * kHW;
#pragma unroll
            for (int j = 0; j < 4; ++j) {
                int prow = t2 * 4 + j;
                int p = p0 + prow; if (p > 195) p = 195;
                int byte = (prow << 10) + (i << 1);
                byte ^= (prow & 7) << 4;
                *(u16*)((char*)imT + byte) = f2bfu(src[p]);
            }
        }
    }
    __syncthreads();

    const int lane = tid & 63;
    const int wn = tid >> 6;
    const int l15 = lane & 15;
    const int l7 = l15 & 7;
    const int kg = lane >> 4;
    const int wbase = (wn * 64 + l15) << 3;

    // ---- GEMM1: xf^T[c][p] = pw x im^T, K=512 ----
    f32x4 acc[4];
#pragma unroll
    for (int fn = 0; fn < 4; ++fn) acc[fn] = f32x4{0.f, 0.f, 0.f, 0.f};
    for (int kk = 0; kk < 16; ++kk) {
        int kb = kk * 32 + kg * 8;
        int byte = (l7 << 10) + (kb << 1);
        byte ^= l7 << 4;
        bf16x8 hb = __builtin_bit_cast(bf16x8, *(const u16x8*)((const char*)imT + byte));
        const u16* wp = pwi + ((((kk << 2) + kg) << 11) + wbase);
#pragma unroll
        for (int fn = 0; fn < 4; ++fn) {
            bf16x8 aw = __builtin_bit_cast(bf16x8, *(const u16x8*)(wp + (fn << 7)));
            acc[fn] = __builtin_amdgcn_mfma_f32_16x16x32_bf16(aw, hb, acc[fn], 0, 0, 0);
        }
    }
    // epilogue: xf = acc + pb -> bf16 xfs[prow][c]; only lanes l15<8 write
    if (l15 < 8) {
#pragma unroll
        for (int fn = 0; fn < 4; ++fn) {
            f32x4 pbv = *(const f32x4*)(pb + wn * 64 + fn * 16 + kg * 4);
            u16x4 pv;
#pragma unroll
            for (int r = 0; r < 4; ++r) pv[r] = f2bfu(acc[fn][r] + pbv[r]);
            int byte = (l15 << 9) + ((wn * 64 + fn * 16 + kg * 4) << 1);
            byte ^= (l15 & 7) << 4;
            *(u16x4*)((char*)xfs + byte) = pv;
        }
    }
    __syncthreads();

    // ---- GEMM2 x2: al / ak (K=256), store fp32 [p][n] ----
    const int p = p0 + l15;
    const bool valid = (l15 < 7);
#pragma unroll
    for (int sel = 0; sel < 2; ++sel) {
        const u16* wsrc = sel ? w1ki : w1li;
        f32x4 a2[4];
#pragma unroll
        for (int fn = 0; fn < 4; ++fn) a2[fn] = f32x4{0.f, 0.f, 0.f, 0.f};
        for (int kk = 0; kk < 8; ++kk) {
            int kb = kk * 32 + kg * 8;
            int byte = (l7 << 9) + (kb << 1);
            byte ^= l7 << 4;
            bf16x8 hb = __builtin_bit_cast(bf16x8, *(const u16x8*)((const char*)xfs + byte));
            const u16* wp = wsrc + ((((kk << 2) + kg) << 11) + wbase);
#pragma unroll
            for (int fn = 0; fn < 4; ++fn) {
                bf16x8 aw = __builtin_bit_cast(bf16x8, *(const u16x8*)(wp + (fn << 7)));
                a2[fn] = __builtin_amdgcn_mfma_f32_16x16x32_bf16(aw, hb, a2[fn], 0, 0, 0);
            }
        }
        if (valid) {
            float* dst = (sel ? ak : al) + ((b * kHW + p) << 8) + wn * 64 + kg * 4;
#pragma unroll
            for (int fn = 0; fn < 4; ++fn) *(f32x4*)(dst + fn * 16) = a2[fn];
        }
    }
}

// ---------------- main v10 (R12-exact, measured 96.6 us, no spill) -----------------
// grid (25 lc, 13 kc, 8 b) = 2600 blocks, block 256 (4 waves; wave = ch quarter).
// Tile: (16 k x 8 l) = 128 pairs x 256 ch. acc[4][8]=128 AGPR; aw[4] preloaded,
// hb streamed one-at-a-time -> peak live ~190 < 256 cap at (256,2).
__global__ __launch_bounds__(256, 2)
void k_main10(const float* __restrict__ ak, const float* __restrict__ al,
              const float* __restrict__ b1, const u16* __restrict__ w2i,
              const float* __restrict__ b2, const u16* __restrict__ w3i,
              const float* __restrict__ b3, float* __restrict__ part) {
    __shared__ u16 smem[128 * 256];  // 64 KB: h1, then h2 in-place
    const int tid = threadIdx.x;
    const int lc = blockIdx.x, kc = blockIdx.y, b = blockIdx.z;
    const int k0 = kc * 16, l0 = lc * 8;

    // ---- build h1 = relu(ak[k]+al[l]+b1) -> bf16 LDS [pair][ch] ----
    {
        const int cc = tid & 31;
        f32x4 c0v = *(const f32x4*)(b1 + (cc << 3));
        f32x4 c1v = *(const f32x4*)(b1 + (cc << 3) + 4);
#pragma unroll
        for (int it = 0; it < 16; ++it) {
            int row = (it * 256 + tid) >> 5;  // 0..127 = (ki-k0)*8 + (li-l0)
            int ki = k0 + (row >> 3); if (ki > 195) ki = 195;
            int li = l0 + (row & 7);  if (li > 195) li = 195;
            const float* akp = ak + ((b * kHW + ki) << 8) + (cc << 3);
            const float* alp = al + ((b * kHW + li) << 8) + (cc << 3);
            f32x4 k0v = *(const f32x4*)akp;
            f32x4 k1v = *(const f32x4*)(akp + 4);
            f32x4 l0v = *(const f32x4*)alp;
            f32x4 l1v = *(const f32x4*)(alp + 4);
            u16x8 v;
#pragma unroll
            for (int j = 0; j < 4; ++j) {
                v[j]     = f2bfu(fmaxf(k0v[j] + l0v[j] + c0v[j], 0.f));
                v[4 + j] = f2bfu(fmaxf(k1v[j] + l1v[j] + c1v[j], 0.f));
            }
            int byte = (row << 9) + (cc << 4);
            byte ^= (row & 7) << 4;
            *(u16x8*)((char*)smem + byte) = v;
        }
    }
    __syncthreads();

    const int lane = tid & 63;
    const int wn = tid >> 6;   // wave = ch quarter 0..3
    const int l15 = lane & 15;
    const int kg = lane >> 4;  // 0..3
    const int wbase = (wn * 64 + l15) << 3;

    f32x4 acc[4][8];  // [fn ch-frag][fm pair-frag], reused for both GEMMs

    // ---- GEMM1: h2^T = w2 x h1^T (aw preloaded, hb streamed) ----
#pragma unroll
    for (int fn = 0; fn < 4; ++fn)
#pragma unroll
        for (int fm = 0; fm < 8; ++fm) acc[fn][fm] = f32x4{0.f, 0.f, 0.f, 0.f};
    for (int kk = 0; kk < 8; ++kk) {
        int kb = kk * 32 + kg * 8;
        const u16* wp = w2i + ((((kk << 2) + kg) << 11) + wbase);
        bf16x8 aw[4];
#pragma unroll
        for (int fn = 0; fn < 4; ++fn)
            aw[fn] = __builtin_bit_cast(bf16x8, *(const u16x8*)(wp + (fn << 7)));
#pragma unroll
        for (int fm = 0; fm < 8; ++fm) {
            int row = fm * 16 + l15;
            int byte = (row << 9) + (kb << 1);
            byte ^= (row & 7) << 4;
            bf16x8 hb = __builtin_bit_cast(bf16x8, *(const u16x8*)((const char*)smem + byte));
#pragma unroll
            for (int fn = 0; fn < 4; ++fn)
                acc[fn][fm] = __builtin_amdgcn_mfma_f32_16x16x32_bf16(aw[fn], hb, acc[fn][fm], 0, 0, 0);
        }
    }
    __syncthreads();

    // ---- epilogue: h2 = relu(D1 + b2) -> bf16 LDS, packed 8B writes ----
#pragma unroll
    for (int fn = 0; fn < 4; ++fn) {
        f32x4 b2v = *(const f32x4*)(b2 + wn * 64 + fn * 16 + kg * 4);
#pragma unroll
        for (int fm = 0; fm < 8; ++fm) {
            int prow = fm * 16 + l15;
            u16x4 pv;
#pragma unroll
            for (int r = 0; r < 4; ++r)
                pv[r] = f2bfu(fmaxf(acc[fn][fm][r] + b2v[r], 0.f));
            int byte = (prow << 9) + ((wn * 64 + fn * 16 + kg * 4) << 1);
            byte ^= (prow & 7) << 4;
            *(u16x4*)((char*)smem + byte) = pv;
        }
    }
    __syncthreads();

    // ---- GEMM2: h3^T = w3 x h2^T ----
#pragma unroll
    for (int fn = 0; fn < 4; ++fn)
#pragma unroll
        for (int fm = 0; fm < 8; ++fm) acc[fn][fm] = f32x4{0.f, 0.f, 0.f, 0.f};
    for (int kk = 0; kk < 8; ++kk) {
        int kb = kk * 32 + kg * 8;
        const u16* wp = w3i + ((((kk << 2) + kg) << 11) + wbase);
        bf16x8 aw[4];
#pragma unroll
        for (int fn = 0; fn < 4; ++fn)
            aw[fn] = __builtin_bit_cast(bf16x8, *(const u16x8*)(wp + (fn << 7)));
#pragma unroll
        for (int fm = 0; fm < 8; ++fm) {
            int row = fm * 16 + l15;
            int byte = (row << 9) + (kb << 1);
            byte ^= (row & 7) << 4;
            bf16x8 hb = __builtin_bit_cast(bf16x8, *(const u16x8*)((const char*)smem + byte));
#pragma unroll
            for (int fn = 0; fn < 4; ++fn)
                acc[fn][fm] = __builtin_amdgcn_mfma_f32_16x16x32_bf16(aw[fn], hb, acc[fn][fm], 0, 0, 0);
        }
    }

    // ---- masked col-sum + 16-lane reduce + store to part ----
    float s[4][4] = {};
#pragma unroll
    for (int fm = 0; fm < 8; ++fm) {
        int pr = fm * 16 + l15;
        int ki = k0 + (pr >> 3);
        int li = l0 + (pr & 7);
        float vm = (ki < kHW && li < kHW) ? 1.f : 0.f;
#pragma unroll
        for (int fn = 0; fn < 4; ++fn) {
            f32x4 b3v = *(const f32x4*)(b3 + wn * 64 + fn * 16 + kg * 4);
#pragma unroll
            for (int r = 0; r < 4; ++r)
                s[fn][r] += vm * fmaxf(acc[fn][fm][r] + b3v[r], 0.f);
        }
    }
#pragma unroll
    for (int fn = 0; fn < 4; ++fn)
#pragma unroll
        for (int r = 0; r < 4; ++r) {
            s[fn][r] += __shfl_xor(s[fn][r], 1);
            s[fn][r] += __shfl_xor(s[fn][r], 2);
            s[fn][r] += __shfl_xor(s[fn][r], 4);
            s[fn][r] += __shfl_xor(s[fn][r], 8);
        }
    if (l15 == 0) {
        int chunkid = (b * kKC + kc) * kLC + lc;
        float* pp = part + chunkid * 256 + wn * 64 + kg * 4;
#pragma unroll
        for (int fn = 0; fn < 4; ++fn)
            *(f32x4*)(pp + fn * 16) = f32x4{s[fn][0], s[fn][1], s[fn][2], s[fn][3]};
    }
}

// ---------------- final reduce: 64 blocks (b x 8 ch-octants) ----------------
__global__ __launch_bounds__(256)
void k_reduce(const float* __restrict__ part, float* __restrict__ out) {
    __shared__ float red[256];
    int b = blockIdx.x >> 3, s = blockIdx.x & 7;
    int c32 = threadIdx.x & 31, stripe = threadIdx.x >> 5;
    int c = s * 32 + c32;
    const float* p = part + b * kChunks * 256 + c;
    float sum = 0.f;
    for (int j = stripe; j < kChunks; j += 8) sum += p[j * 256];
    red[threadIdx.x] = sum;
    __syncthreads();
    if (threadIdx.x < 32) {
        float t = 0.f;
#pragma unroll
        for (int st = 0; st < 8; ++st) t += red[st * 32 + c32];
        out[b * 256 + c] = t;
    }
}

extern "C" void kernel_launch(void* const* d_in, const int* in_sizes, int n_in,
                              void* d_out, int out_size, void* d_ws, size_t ws_size,
                              hipStream_t stream) {
    const float* im = (const float*)d_in[0];
    const float* pw = (const float*)d_in[3];
    const float* pb = (const float*)d_in[4];
    const float* w1 = (const float*)d_in[5];
    const float* b1 = (const float*)d_in[6];
    const float* w2 = (const float*)d_in[7];
    const float* b2 = (const float*)d_in[8];
    const float* w3 = (const float*)d_in[9];
    const float* b3 = (const float*)d_in[10];
    float* out = (float*)d_out;

    float* al  = (float*)d_ws;            // 8*196*256
    float* ak  = al + 8 * 196 * 256;
    u16* pwi  = (u16*)(ak + 8 * 196 * 256);  // [64 k8-blk][256 n][8 k]
    u16* w1li = pwi + 512 * 256;             // [32 k8-blk][256 n][8 k]
    u16* w1ki = w1li + 256 * 256;
    u16* w2i  = w1ki + 256 * 256;
    u16* w3i  = w2i + 256 * 256;
    float* part = (float*)(w3i + 256 * 256); // [8*325][256] = 2.66 MB

    hipLaunchKernelGGL(k_prep, dim3(1280), dim3(256), 0, stream,
                       pw, pwi, w1, w1li, w1ki, w2, w2i, w3, w3i);
    hipLaunchKernelGGL(k_xa4, dim3(28, 8), dim3(256), 0, stream,
                       im, pwi, pb, w1li, w1ki, al, ak);
    hipLaunchKernelGGL(k_main10, dim3(kLC, kKC, 8), dim3(256), 0, stream,
                       ak, al, b1, w2i, b2, w3i, b3, part);
    hipLaunchKernelGGL(k_reduce, dim3(64), dim3(256), 0, stream, part, out);
}

// Round 18
// 123.270 us; speedup vs baseline: 1.1146x; 1.0516x over previous
//
#include <hip/hip_runtime.h>
#include <hip/hip_bf16.h>

typedef unsigned short u16;
typedef float  f32x4  __attribute__((ext_vector_type(4)));
typedef __bf16 bf16x8 __attribute__((ext_vector_type(8)));
typedef unsigned short u16x8 __attribute__((ext_vector_type(8)));
typedef unsigned short u16x4 __attribute__((ext_vector_type(4)));

__device__ __forceinline__ u16 f2bfu(float f) {
    __hip_bfloat16 h = __float2bfloat16(f);
    return __builtin_bit_cast(unsigned short, h);
}

constexpr int kHW = 196;   // 14*14
constexpr int kKC = 13;    // ceil(196/16) k-chunks (16 k rows per tile)
constexpr int kLC = 25;    // ceil(196/8)  l-chunks (8 l rows per tile)
constexpr int kChunks = kKC * kLC;  // 325 per batch

// ---------------- prep: interleave weights [k>>3][n][k8] bf16 (coalesced reads) ----
__global__ __launch_bounds__(256)
void k_prep(const float* __restrict__ pw, u16* __restrict__ pwi,
            const float* __restrict__ w1, u16* __restrict__ w1li, u16* __restrict__ w1ki,
            const float* __restrict__ w2, u16* __restrict__ w2i,
            const float* __restrict__ w3, u16* __restrict__ w3i) {
    int id = blockIdx.x;
    int t = threadIdx.x;
    if (id < 256) {
        int n = id;
#pragma unroll
        for (int h = 0; h < 2; ++h) {
            int k = h * 256 + t;
            pwi[((k >> 3) << 11) + (n << 3) + (k & 7)] = f2bfu(pw[n * 512 + k]);
        }
    } else {
        int k = (id - 256) & 255;
        int idx = ((k >> 3) << 11) + (t << 3) + (k & 7);
        if (id < 512)       w1li[idx] = f2bfu(w1[k * 256 + t]);
        else if (id < 768)  w1ki[idx] = f2bfu(w1[(k + 256) * 256 + t]);
        else if (id < 1024) w2i[idx]  = f2bfu(w2[k * 256 + t]);
        else                w3i[idx]  = f2bfu(w3[k * 256 + t]);
    }
}

// ---------------- MFMA prologue: xf then al/ak. grid (14, 8), 256 thr ----------------
__global__ __launch_bounds__(256, 2)
void k_xa3(const float* __restrict__ im, const u16* __restrict__ pwi,
           const float* __restrict__ pb, const u16* __restrict__ w1li,
           const u16* __restrict__ w1ki, float* __restrict__ al,
           float* __restrict__ ak) {
    __shared__ u16 imT[16 * 512];   // [p][i] bf16, swizzled rows (1KB), 16KB
    __shared__ u16 xfs[16 * 256];   // [p][c] bf16, swizzled rows (512B), 8KB
    const int tid = threadIdx.x;
    const int b = blockIdx.y;
    const int p0 = blockIdx.x * 14;

    {
        int t4 = tid & 3;
        int ibase = tid >> 2;
#pragma unroll
        for (int it = 0; it < 8; ++it) {
            int i = it * 64 + ibase;
            const float* src = im + (b * 512 + i) * kHW;
#pragma unroll
            for (int j = 0; j < 4; ++j) {
                int prow = t4 * 4 + j;
                int p = p0 + prow; if (p > 195) p = 195;
                int byte = (prow << 10) + (i << 1);
                byte ^= (prow & 7) << 4;
                *(u16*)((char*)imT + byte) = f2bfu(src[p]);
            }
        }
    }
    __syncthreads();

    const int lane = tid & 63;
    const int wn = tid >> 6;
    const int l15 = lane & 15;
    const int kg = lane >> 4;
    const int wbase = (wn * 64 + l15) << 3;

    f32x4 acc[4];
#pragma unroll
    for (int fn = 0; fn < 4; ++fn) acc[fn] = f32x4{0.f, 0.f, 0.f, 0.f};
    for (int kk = 0; kk < 16; ++kk) {
        int kb = kk * 32 + kg * 8;
        int byte = (l15 << 10) + (kb << 1);
        byte ^= (l15 & 7) << 4;
        bf16x8 hb = __builtin_bit_cast(bf16x8, *(const u16x8*)((const char*)imT + byte));
        const u16* wp = pwi + ((((kk << 2) + kg) << 11) + wbase);
#pragma unroll
        for (int fn = 0; fn < 4; ++fn) {
            bf16x8 aw = __builtin_bit_cast(bf16x8, *(const u16x8*)(wp + (fn << 7)));
            acc[fn] = __builtin_amdgcn_mfma_f32_16x16x32_bf16(aw, hb, acc[fn], 0, 0, 0);
        }
    }
#pragma unroll
    for (int fn = 0; fn < 4; ++fn) {
        f32x4 pbv = *(const f32x4*)(pb + wn * 64 + fn * 16 + kg * 4);
        u16x4 pv;
#pragma unroll
        for (int r = 0; r < 4; ++r) pv[r] = f2bfu(acc[fn][r] + pbv[r]);
        int byte = (l15 << 9) + ((wn * 64 + fn * 16 + kg * 4) << 1);
        byte ^= (l15 & 7) << 4;
        *(u16x4*)((char*)xfs + byte) = pv;
    }
    __syncthreads();

    const int p = p0 + l15;
    const bool valid = (l15 < 14) && (p < kHW);
#pragma unroll
    for (int sel = 0; sel < 2; ++sel) {
        const u16* wsrc = sel ? w1ki : w1li;
        f32x4 a2[4];
#pragma unroll
        for (int fn = 0; fn < 4; ++fn) a2[fn] = f32x4{0.f, 0.f, 0.f, 0.f};
        for (int kk = 0; kk < 8; ++kk) {
            int kb = kk * 32 + kg * 8;
            int byte = (l15 << 9) + (kb << 1);
            byte ^= (l15 & 7) << 4;
            bf16x8 hb = __builtin_bit_cast(bf16x8, *(const u16x8*)((const char*)xfs + byte));
            const u16* wp = wsrc + ((((kk << 2) + kg) << 11) + wbase);
#pragma unroll
            for (int fn = 0; fn < 4; ++fn) {
                bf16x8 aw = __builtin_bit_cast(bf16x8, *(const u16x8*)(wp + (fn << 7)));
                a2[fn] = __builtin_amdgcn_mfma_f32_16x16x32_bf16(aw, hb, a2[fn], 0, 0, 0);
            }
        }
        if (valid) {
            float* dst = (sel ? ak : al) + ((b * kHW + p) << 8) + wn * 64 + kg * 4;
#pragma unroll
            for (int fn = 0; fn < 4; ++fn) *(f32x4*)(dst + fn * 16) = a2[fn];
        }
    }
}

// ---------------- main v10 (R12-exact, measured 96.6-96.8 us, no spill) ------------
__global__ __launch_bounds__(256, 2)
void k_main10(const float* __restrict__ ak, const float* __restrict__ al,
              const float* __restrict__ b1, const u16* __restrict__ w2i,
              const float* __restrict__ b2, const u16* __restrict__ w3i,
              const float* __restrict__ b3, float* __restrict__ part) {
    __shared__ u16 smem[128 * 256];  // 64 KB: h1, then h2 in-place
    const int tid = threadIdx.x;
    const int lc = blockIdx.x, kc = blockIdx.y, b = blockIdx.z;
    const int k0 = kc * 16, l0 = lc * 8;

    {
        const int cc = tid & 31;
        f32x4 c0v = *(const f32x4*)(b1 + (cc << 3));
        f32x4 c1v = *(const f32x4*)(b1 + (cc << 3) + 4);
#pragma unroll
        for (int it = 0; it < 16; ++it) {
            int row = (it * 256 + tid) >> 5;
            int ki = k0 + (row >> 3); if (ki > 195) ki = 195;
            int li = l0 + (row & 7);  if (li > 195) li = 195;
            const float* akp = ak + ((b * kHW + ki) << 8) + (cc << 3);
            const float* alp = al + ((b * kHW + li) << 8) + (cc << 3);
            f32x4 k0v = *(const f32x4*)akp;
            f32x4 k1v = *(const f32x4*)(akp + 4);
            f32x4 l0v = *(const f32x4*)alp;
            f32x4 l1v = *(const f32x4*)(alp + 4);
            u16x8 v;
#pragma unroll
            for (int j = 0; j < 4; ++j) {
                v[j]     = f2bfu(fmaxf(k0v[j] + l0v[j] + c0v[j], 0.f));
                v[4 + j] = f2bfu(fmaxf(k1v[j] + l1v[j] + c1v[j], 0.f));
            }
            int byte = (row << 9) + (cc << 4);
            byte ^= (row & 7) << 4;
            *(u16x8*)((char*)smem + byte) = v;
        }
    }
    __syncthreads();

    const int lane = tid & 63;
    const int wn = tid >> 6;
    const int l15 = lane & 15;
    const int kg = lane >> 4;
    const int wbase = (wn * 64 + l15) << 3;

    f32x4 acc[4][8];

#pragma unroll
    for (int fn = 0; fn < 4; ++fn)
#pragma unroll
        for (int fm = 0; fm < 8; ++fm) acc[fn][fm] = f32x4{0.f, 0.f, 0.f, 0.f};
    for (int kk = 0; kk < 8; ++kk) {
        int kb = kk * 32 + kg * 8;
        const u16* wp = w2i + ((((kk << 2) + kg) << 11) + wbase);
        bf16x8 aw[4];
#pragma unroll
        for (int fn = 0; fn < 4; ++fn)
            aw[fn] = __builtin_bit_cast(bf16x8, *(const u16x8*)(wp + (fn << 7)));
#pragma unroll
        for (int fm = 0; fm < 8; ++fm) {
            int row = fm * 16 + l15;
            int byte = (row << 9) + (kb << 1);
            byte ^= (row & 7) << 4;
            bf16x8 hb = __builtin_bit_cast(bf16x8, *(const u16x8*)((const char*)smem + byte));
#pragma unroll
            for (int fn = 0; fn < 4; ++fn)
                acc[fn][fm] = __builtin_amdgcn_mfma_f32_16x16x32_bf16(aw[fn], hb, acc[fn][fm], 0, 0, 0);
        }
    }
    __syncthreads();

#pragma unroll
    for (int fn = 0; fn < 4; ++fn) {
        f32x4 b2v = *(const f32x4*)(b2 + wn * 64 + fn * 16 + kg * 4);
#pragma unroll
        for (int fm = 0; fm < 8; ++fm) {
            int prow = fm * 16 + l15;
            u16x4 pv;
#pragma unroll
            for (int r = 0; r < 4; ++r)
                pv[r] = f2bfu(fmaxf(acc[fn][fm][r] + b2v[r], 0.f));
            int byte = (prow << 9) + ((wn * 64 + fn * 16 + kg * 4) << 1);
            byte ^= (prow & 7) << 4;
            *(u16x4*)((char*)smem + byte) = pv;
        }
    }
    __syncthreads();

#pragma unroll
    for (int fn = 0; fn < 4; ++fn)
#pragma unroll
        for (int fm = 0; fm < 8; ++fm) acc[fn][fm] = f32x4{0.f, 0.f, 0.f, 0.f};
    for (int kk = 0; kk < 8; ++kk) {
        int kb = kk * 32 + kg * 8;
        const u16* wp = w3i + ((((kk << 2) + kg) << 11) + wbase);
        bf16x8 aw[4];
#pragma unroll
        for (int fn = 0; fn < 4; ++fn)
            aw[fn] = __builtin_bit_cast(bf16x8, *(const u16x8*)(wp + (fn << 7)));
#pragma unroll
        for (int fm = 0; fm < 8; ++fm) {
            int row = fm * 16 + l15;
            int byte = (row << 9) + (kb << 1);
            byte ^= (row & 7) << 4;
            bf16x8 hb = __builtin_bit_cast(bf16x8, *(const u16x8*)((const char*)smem + byte));
#pragma unroll
            for (int fn = 0; fn < 4; ++fn)
                acc[fn][fm] = __builtin_amdgcn_mfma_f32_16x16x32_bf16(aw[fn], hb, acc[fn][fm], 0, 0, 0);
        }
    }

    float s[4][4] = {};
#pragma unroll
    for (int fm = 0; fm < 8; ++fm) {
        int pr = fm * 16 + l15;
        int ki = k0 + (pr >> 3);
        int li = l0 + (pr & 7);
        float vm = (ki < kHW && li < kHW) ? 1.f : 0.f;
#pragma unroll
        for (int fn = 0; fn < 4; ++fn) {
            f32x4 b3v = *(const f32x4*)(b3 + wn * 64 + fn * 16 + kg * 4);
#pragma unroll
            for (int r = 0; r < 4; ++r)
                s[fn][r] += vm * fmaxf(acc[fn][fm][r] + b3v[r], 0.f);
        }
    }
#pragma unroll
    for (int fn = 0; fn < 4; ++fn)
#pragma unroll
        for (int r = 0; r < 4; ++r) {
            s[fn][r] += __shfl_xor(s[fn][r], 1);
            s[fn][r] += __shfl_xor(s[fn][r], 2);
            s[fn][r] += __shfl_xor(s[fn][r], 4);
            s[fn][r] += __shfl_xor(s[fn][r], 8);
        }
    if (l15 == 0) {
        int chunkid = (b * kKC + kc) * kLC + lc;
        float* pp = part + chunkid * 256 + wn * 64 + kg * 4;
#pragma unroll
        for (int fn = 0; fn < 4; ++fn)
            *(f32x4*)(pp + fn * 16) = f32x4{s[fn][0], s[fn][1], s[fn][2], s[fn][3]};
    }
}

// ---------------- final reduce: 64 blocks (b x 8 ch-octants) ----------------
__global__ __launch_bounds__(256)
void k_reduce(const float* __restrict__ part, float* __restrict__ out) {
    __shared__ float red[256];
    int b = blockIdx.x >> 3, s = blockIdx.x & 7;
    int c32 = threadIdx.x & 31, stripe = threadIdx.x >> 5;
    int c = s * 32 + c32;
    const float* p = part + b * kChunks * 256 + c;
    float sum = 0.f;
    for (int j = stripe; j < kChunks; j += 8) sum += p[j * 256];
    red[threadIdx.x] = sum;
    __syncthreads();
    if (threadIdx.x < 32) {
        float t = 0.f;
#pragma unroll
        for (int st = 0; st < 8; ++st) t += red[st * 32 + c32];
        out[b * 256 + c] = t;
    }
}

extern "C" void kernel_launch(void* const* d_in, const int* in_sizes, int n_in,
                              void* d_out, int out_size, void* d_ws, size_t ws_size,
                              hipStream_t stream) {
    const float* im = (const float*)d_in[0];
    const float* pw = (const float*)d_in[3];
    const float* pb = (const float*)d_in[4];
    const float* w1 = (const float*)d_in[5];
    const float* b1 = (const float*)d_in[6];
    const float* w2 = (const float*)d_in[7];
    const float* b2 = (const float*)d_in[8];
    const float* w3 = (const float*)d_in[9];
    const float* b3 = (const float*)d_in[10];
    float* out = (float*)d_out;

    float* al  = (float*)d_ws;            // 8*196*256
    float* ak  = al + 8 * 196 * 256;
    u16* pwi  = (u16*)(ak + 8 * 196 * 256);  // [64 k8-blk][256 n][8 k]
    u16* w1li = pwi + 512 * 256;             // [32 k8-blk][256 n][8 k]
    u16* w1ki = w1li + 256 * 256;
    u16* w2i  = w1ki + 256 * 256;
    u16* w3i  = w2i + 256 * 256;
    float* part = (float*)(w3i + 256 * 256); // [8*325][256] = 2.66 MB

    hipLaunchKernelGGL(k_prep, dim3(1280), dim3(256), 0, stream,
                       pw, pwi, w1, w1li, w1ki, w2, w2i, w3, w3i);
    hipLaunchKernelGGL(k_xa3, dim3(14, 8), dim3(256), 0, stream,
                       im, pwi, pb, w1li, w1ki, al, ak);
    hipLaunchKernelGGL(k_main10, dim3(kLC, kKC, 8), dim3(256), 0, stream,
                       ak, al, b1, w2i, b2, w3i, b3, part);
    hipLaunchKernelGGL(k_reduce, dim3(64), dim3(256), 0, stream, part, out);
}